// Round 3
// baseline (623.027 us; speedup 1.0000x reference)
//
#include <hip/hip_runtime.h>
#include <cstdint>
#include <cstddef>

// ---------------------------------------------------------------------------
// GAttn round 2 (resubmit — two consecutive infra timeouts, never benched):
// bf16-MFMA pipeline, transposed (n-major) intermediate world.
//   T0  stats   : mean/rstd per (b,c)
//   T1  xnT     : normalize+transpose -> xnT[b][n][c] bf16
//   T2  conv1   : gelu(W@xn+b) for q1,k1 -> y1qk[n][512]; v,g -> yvg[n][512]
//   T3  conv2   : softplus(W@.+b) -> qkT[n][512] (q|k) + ksum atomics (k)
//   T3t         : transpose k,v to c-major kC,vC
//   T4  kv      : kv[c][d] = sum_n k[c,n] v[d,n]   (fp32 atomics, 32 chunks)
//   T4c         : kvT16[d][c] = bf16(kv[c][d]/16)
//   T5  z       : z = 1/(q.ksum/16 + N)
//   T6  final   : t=q.kvT16 ; s=(t+v)*z*g ; out = Wo@s + bo
// ---------------------------------------------------------------------------

#define DI __device__ __forceinline__

typedef __attribute__((ext_vector_type(8))) short bf16x8;
typedef __attribute__((ext_vector_type(4))) short bf16x4;
typedef __attribute__((ext_vector_type(4))) float f32x4;

static constexpr int Cc = 256;
static constexpr int NN = 16384;

DI float bf2f(short s){ unsigned int u = ((unsigned int)(unsigned short)s) << 16; float f; __builtin_memcpy(&f, &u, 4); return f; }
DI short f2bf(float f){ unsigned int u; __builtin_memcpy(&u, &f, 4); u += 0x7fffu + ((u >> 16) & 1u); return (short)(u >> 16); }
DI float geluf(float x){ return 0.5f * x * (1.0f + erff(x * 0.70710678118654752f)); }
DI float softplusf(float x){ return fmaxf(x, 0.0f) + log1pf(__expf(-fabsf(x))); }

// ---------------- T0: instance-norm stats ----------------
__global__ __launch_bounds__(256) void t0_stats(const float* __restrict__ x,
                                                float* __restrict__ mu, float* __restrict__ rstd)
{
    int row = blockIdx.x;                       // b*256 + c
    const float4* p = (const float4*)(x + (size_t)row * NN);
    float s = 0.f, ss = 0.f;
    for (int i = threadIdx.x; i < NN/4; i += 256){
        float4 v = p[i];
        s  += v.x + v.y + v.z + v.w;
        ss += v.x*v.x + v.y*v.y + v.z*v.z + v.w*v.w;
    }
    #pragma unroll
    for (int o = 32; o; o >>= 1){ s += __shfl_down(s, o); ss += __shfl_down(ss, o); }
    __shared__ float a0[4], a1[4];
    int w = threadIdx.x >> 6;
    if ((threadIdx.x & 63) == 0){ a0[w] = s; a1[w] = ss; }
    __syncthreads();
    if (threadIdx.x == 0){
        float S = a0[0]+a0[1]+a0[2]+a0[3], SS = a1[0]+a1[1]+a1[2]+a1[3];
        float m = S * (1.f/NN);
        float var = SS * (1.f/NN) - m*m;
        mu[row] = m;
        rstd[row] = rsqrtf(var + 1e-5f);
    }
}

// ---------------- T1: normalize + transpose -> xnT[b][n][c] ----------------
__global__ __launch_bounds__(256) void t1_xnT(const float* __restrict__ x,
                                              const float* __restrict__ mu, const float* __restrict__ rstd,
                                              short* __restrict__ xnT)
{
    int n0 = blockIdx.x * 64, c0 = blockIdx.y * 64, b = blockIdx.z;
    __shared__ __align__(16) short lds[64*72];
    int t = threadIdx.x;
    // phase 1: coalesced read along n, swizzled write lds[c][n]
    #pragma unroll
    for (int i = 0; i < 4; i++){
        int idx = i*256 + t;
        int c  = idx >> 4;          // 0..63
        int n4 = idx & 15;          // float4 along n
        int cg = b*Cc + c0 + c;
        float4 v = *(const float4*)(x + (size_t)cg*NN + n0 + n4*4);
        float m = mu[cg], rs = rstd[cg];
        int key = (c ^ (c >> 3)) & 7;
        int blk = (n4 >> 1) ^ key;
        bf16x4 pk = { f2bf((v.x-m)*rs), f2bf((v.y-m)*rs), f2bf((v.z-m)*rs), f2bf((v.w-m)*rs) };
        *(bf16x4*)(&lds[c*72 + blk*8 + (n4&1)*4]) = pk;
    }
    __syncthreads();
    // phase 2: gather 8 c for fixed n, coalesced short8 store
    #pragma unroll
    for (int i = 0; i < 2; i++){
        int idx = i*256 + t;
        int n  = idx >> 3;          // 0..63
        int c8 = idx & 7;
        bf16x8 pk;
        #pragma unroll
        for (int j = 0; j < 8; j++){
            int c = c8*8 + j;
            int key = (c ^ (c >> 3)) & 7;
            pk[j] = lds[c*72 + (((n >> 3) ^ key))*8 + (n & 7)];
        }
        *(bf16x8*)(xnT + ((size_t)(b*NN + n0 + n))*Cc + c0 + c8*8) = pk;
    }
}

// ---------------- T2: conv1 (4 branches, gelu) ----------------
__global__ __launch_bounds__(256) void t2_conv1(const short* __restrict__ xnT,
    const float* __restrict__ Wq1, const float* __restrict__ bq1,
    const float* __restrict__ Wk1, const float* __restrict__ bk1,
    const float* __restrict__ Wv,  const float* __restrict__ bv,
    const float* __restrict__ Wg,  const float* __restrict__ bg,
    short* __restrict__ y1qk, short* __restrict__ yvg)
{
    int n0 = blockIdx.x * 128;
    int stile = blockIdx.y;             // 0..7
    int b = blockIdx.z;
    int branch = stile >> 1;
    const float* W  = branch==0 ? Wq1 : branch==1 ? Wk1 : branch==2 ? Wv : Wg;
    const float* bs = branch==0 ? bq1 : branch==1 ? bk1 : branch==2 ? bv : bg;
    int s0b = (stile & 1) * 128;        // row offset inside branch weight
    short* dst; int dcol;
    if (stile < 4){ dst = y1qk; dcol = stile*128; } else { dst = yvg; dcol = (stile-4)*128; }

    __shared__ __align__(16) short Al[128*40];
    __shared__ __align__(16) short Bl[128*40];
    int t = threadIdx.x, lane = t & 63, wid = t >> 6;
    int wm = (wid & 1) * 64, wn = (wid >> 1) * 64;
    int l15 = lane & 15, g = lane >> 4;

    f32x4 acc[4][4];
    #pragma unroll
    for (int i=0;i<4;i++)
        #pragma unroll
        for (int j=0;j<4;j++){ acc[i][j][0]=0.f; acc[i][j][1]=0.f; acc[i][j][2]=0.f; acc[i][j][3]=0.f; }

    const short* xb = xnT + (size_t)(b*NN + n0) * Cc;

    for (int k0 = 0; k0 < 256; k0 += 32){
        __syncthreads();
        #pragma unroll
        for (int i = 0; i < 2; i++){            // A: xnT 128n x 32c
            int idx = i*256 + t;
            int r = idx >> 2, c8 = idx & 3;
            *(bf16x8*)(&Al[r*40 + c8*8]) = *(const bf16x8*)(xb + (size_t)r*Cc + k0 + c8*8);
        }
        #pragma unroll
        for (int i = 0; i < 4; i++){            // B: W 128s x 32c (fp32->bf16)
            int idx = i*256 + t;
            int r = idx >> 3, c4 = idx & 7;
            float4 v = *(const float4*)(W + (size_t)(s0b + r)*Cc + k0 + c4*4);
            bf16x4 pk = { f2bf(v.x), f2bf(v.y), f2bf(v.z), f2bf(v.w) };
            *(bf16x4*)(&Bl[r*40 + c4*4]) = pk;
        }
        __syncthreads();
        bf16x8 bfr[4];
        #pragma unroll
        for (int ni = 0; ni < 4; ni++) bfr[ni] = *(const bf16x8*)(&Bl[(wn + ni*16 + l15)*40 + g*8]);
        #pragma unroll
        for (int mi = 0; mi < 4; mi++){
            bf16x8 a = *(const bf16x8*)(&Al[(wm + mi*16 + l15)*40 + g*8]);
            #pragma unroll
            for (int ni = 0; ni < 4; ni++)
                acc[mi][ni] = __builtin_amdgcn_mfma_f32_16x16x32_bf16(a, bfr[ni], acc[mi][ni], 0, 0, 0);
        }
    }
    short* outb = dst + (size_t)(b*NN + n0) * 512 + dcol;
    #pragma unroll
    for (int mi = 0; mi < 4; mi++)
        #pragma unroll
        for (int ni = 0; ni < 4; ni++){
            int coll = wn + ni*16 + l15;
            float bias = bs[s0b + coll];
            #pragma unroll
            for (int r = 0; r < 4; r++){
                int row = wm + mi*16 + g*4 + r;
                outb[(size_t)row*512 + coll] = f2bf(geluf(acc[mi][ni][r] + bias));
            }
        }
}

// ---------------- T3: conv2 (q,k softplus) + ksum ----------------
__global__ __launch_bounds__(256) void t3_conv2(const short* __restrict__ y1qk,
    const float* __restrict__ Wq2, const float* __restrict__ bq2,
    const float* __restrict__ Wk2, const float* __restrict__ bk2,
    short* __restrict__ qkT, float* __restrict__ ksum)
{
    int n0 = blockIdx.x * 128;
    int stile = blockIdx.y;             // 0..3
    int b = blockIdx.z;
    int branch = stile >> 1;            // 0=q, 1=k
    const float* W  = branch ? Wk2 : Wq2;
    const float* bs = branch ? bk2 : bq2;
    int ksrc = branch * 256;            // q1 at cols 0..255, k1 at 256..511
    int s0b = (stile & 1) * 128;

    __shared__ __align__(16) short Al[128*40];
    __shared__ __align__(16) short Bl[128*40];
    int t = threadIdx.x, lane = t & 63, wid = t >> 6;
    int wm = (wid & 1) * 64, wn = (wid >> 1) * 64;
    int l15 = lane & 15, g = lane >> 4;

    f32x4 acc[4][4];
    #pragma unroll
    for (int i=0;i<4;i++)
        #pragma unroll
        for (int j=0;j<4;j++){ acc[i][j][0]=0.f; acc[i][j][1]=0.f; acc[i][j][2]=0.f; acc[i][j][3]=0.f; }

    const short* src = y1qk + (size_t)(b*NN + n0) * 512 + ksrc;

    for (int k0 = 0; k0 < 256; k0 += 32){
        __syncthreads();
        #pragma unroll
        for (int i = 0; i < 2; i++){
            int idx = i*256 + t;
            int r = idx >> 2, c8 = idx & 3;
            *(bf16x8*)(&Al[r*40 + c8*8]) = *(const bf16x8*)(src + (size_t)r*512 + k0 + c8*8);
        }
        #pragma unroll
        for (int i = 0; i < 4; i++){
            int idx = i*256 + t;
            int r = idx >> 3, c4 = idx & 7;
            float4 v = *(const float4*)(W + (size_t)(s0b + r)*Cc + k0 + c4*4);
            bf16x4 pk = { f2bf(v.x), f2bf(v.y), f2bf(v.z), f2bf(v.w) };
            *(bf16x4*)(&Bl[r*40 + c4*4]) = pk;
        }
        __syncthreads();
        bf16x8 bfr[4];
        #pragma unroll
        for (int ni = 0; ni < 4; ni++) bfr[ni] = *(const bf16x8*)(&Bl[(wn + ni*16 + l15)*40 + g*8]);
        #pragma unroll
        for (int mi = 0; mi < 4; mi++){
            bf16x8 a = *(const bf16x8*)(&Al[(wm + mi*16 + l15)*40 + g*8]);
            #pragma unroll
            for (int ni = 0; ni < 4; ni++)
                acc[mi][ni] = __builtin_amdgcn_mfma_f32_16x16x32_bf16(a, bfr[ni], acc[mi][ni], 0, 0, 0);
        }
    }
    short* outb = qkT + (size_t)(b*NN + n0) * 512 + branch*256 + s0b;
    float csum[4] = {0.f, 0.f, 0.f, 0.f};
    #pragma unroll
    for (int mi = 0; mi < 4; mi++)
        #pragma unroll
        for (int ni = 0; ni < 4; ni++){
            int coll = wn + ni*16 + l15;
            float bias = bs[s0b + coll];
            #pragma unroll
            for (int r = 0; r < 4; r++){
                int row = wm + mi*16 + g*4 + r;
                float val = softplusf(acc[mi][ni][r] + bias);
                outb[(size_t)row*512 + coll] = f2bf(val);
                csum[ni] += val;
            }
        }
    if (branch == 1){
        #pragma unroll
        for (int ni = 0; ni < 4; ni++){
            float v = csum[ni];
            v += __shfl_xor(v, 16);
            v += __shfl_xor(v, 32);
            if (g == 0) atomicAdd(&ksum[b*Cc + s0b + wn + ni*16 + l15], v);
        }
    }
}

// ---------------- T3t: transpose k,v to c-major ----------------
__global__ __launch_bounds__(256) void t3t_transpose(const short* __restrict__ qkT, const short* __restrict__ yvg,
                                                     short* __restrict__ kC, short* __restrict__ vC)
{
    int n0 = blockIdx.x * 64;
    int c0 = blockIdx.y * 64;
    int b  = blockIdx.z >> 1;
    int which = blockIdx.z & 1;
    const short* src; short* dst;
    if (which == 0){ src = qkT + (size_t)(b*NN + n0)*512 + 256 + c0; dst = kC + (size_t)(b*Cc + c0)*NN + n0; }
    else           { src = yvg + (size_t)(b*NN + n0)*512 +   0 + c0; dst = vC + (size_t)(b*Cc + c0)*NN + n0; }
    __shared__ __align__(16) short lds[64*72];
    int t = threadIdx.x;
    #pragma unroll
    for (int i = 0; i < 2; i++){
        int idx = i*256 + t;
        int n = idx >> 3, c8 = idx & 7;
        bf16x8 v = *(const bf16x8*)(src + (size_t)n*512 + c8*8);
        int key = (n ^ (n >> 3)) & 7;
        *(bf16x8*)(&lds[n*72 + (c8 ^ key)*8]) = v;
    }
    __syncthreads();
    #pragma unroll
    for (int i = 0; i < 2; i++){
        int idx = i*256 + t;
        int c = idx >> 3, n8 = idx & 7;
        bf16x8 pk;
        #pragma unroll
        for (int j = 0; j < 8; j++){
            int n = n8*8 + j;
            int key = (n ^ (n >> 3)) & 7;
            pk[j] = lds[n*72 + (((c >> 3) ^ key))*8 + (c & 7)];
        }
        *(bf16x8*)(dst + (size_t)c*NN + n8*8) = pk;
    }
}

// ---------------- T4: kv GEMM (atomic K-split) ----------------
__global__ __launch_bounds__(256) void t4_kv(const short* __restrict__ kC, const short* __restrict__ vC,
                                             float* __restrict__ kv)
{
    int m0 = blockIdx.x * 128;          // c
    int d0 = blockIdx.y * 128;          // d
    int b  = blockIdx.z >> 5;
    int nb = (blockIdx.z & 31) * 512;

    __shared__ __align__(16) short Al[128*40];
    __shared__ __align__(16) short Bl[128*40];
    int t = threadIdx.x, lane = t & 63, wid = t >> 6;
    int wm = (wid & 1) * 64, wn = (wid >> 1) * 64;
    int l15 = lane & 15, g = lane >> 4;

    f32x4 acc[4][4];
    #pragma unroll
    for (int i=0;i<4;i++)
        #pragma unroll
        for (int j=0;j<4;j++){ acc[i][j][0]=0.f; acc[i][j][1]=0.f; acc[i][j][2]=0.f; acc[i][j][3]=0.f; }

    const short* ka = kC + (size_t)(b*Cc + m0)*NN + nb;
    const short* vb = vC + (size_t)(b*Cc + d0)*NN + nb;

    for (int k0 = 0; k0 < 512; k0 += 32){
        __syncthreads();
        #pragma unroll
        for (int i = 0; i < 2; i++){
            int idx = i*256 + t;
            int r = idx >> 2, c8 = idx & 3;
            *(bf16x8*)(&Al[r*40 + c8*8]) = *(const bf16x8*)(ka + (size_t)r*NN + k0 + c8*8);
            *(bf16x8*)(&Bl[r*40 + c8*8]) = *(const bf16x8*)(vb + (size_t)r*NN + k0 + c8*8);
        }
        __syncthreads();
        bf16x8 bfr[4];
        #pragma unroll
        for (int ni = 0; ni < 4; ni++) bfr[ni] = *(const bf16x8*)(&Bl[(wn + ni*16 + l15)*40 + g*8]);
        #pragma unroll
        for (int mi = 0; mi < 4; mi++){
            bf16x8 a = *(const bf16x8*)(&Al[(wm + mi*16 + l15)*40 + g*8]);
            #pragma unroll
            for (int ni = 0; ni < 4; ni++)
                acc[mi][ni] = __builtin_amdgcn_mfma_f32_16x16x32_bf16(a, bfr[ni], acc[mi][ni], 0, 0, 0);
        }
    }
    #pragma unroll
    for (int mi = 0; mi < 4; mi++)
        #pragma unroll
        for (int ni = 0; ni < 4; ni++){
            int coll = wn + ni*16 + l15;
            #pragma unroll
            for (int r = 0; r < 4; r++){
                int row = wm + mi*16 + g*4 + r;
                atomicAdd(&kv[((size_t)b*Cc + m0 + row)*Cc + d0 + coll], acc[mi][ni][r]);
            }
        }
}

// ---------------- T4c: kvT16[d][c] = bf16(kv[c][d]/16) ----------------
__global__ __launch_bounds__(256) void t4c_kvT(const float* __restrict__ kv, short* __restrict__ kvT16)
{
    int d = blockIdx.x, b = blockIdx.y, c = threadIdx.x;
    float v = kv[((size_t)b*Cc + c)*Cc + d] * 0.0625f;
    kvT16[((size_t)b*Cc + d)*Cc + c] = f2bf(v);
}

// ---------------- T5: z = 1/(q.ksum/16 + N) ----------------
__global__ __launch_bounds__(256) void t5_z(const short* __restrict__ qkT, const float* __restrict__ ksum,
                                            float* __restrict__ z)
{
    int b = blockIdx.y;
    int n0 = blockIdx.x * 32;
    __shared__ float ks[256];
    int t = threadIdx.x;
    ks[t] = ksum[b*Cc + t];
    __syncthreads();
    int row = n0 + (t >> 3), l8 = t & 7;
    const short* q = qkT + (size_t)(b*NN + row)*512;
    float acc = 0.f;
    #pragma unroll
    for (int i = 0; i < 4; i++){
        int c8 = i*8 + l8;
        bf16x8 v = *(const bf16x8*)(q + c8*8);
        #pragma unroll
        for (int j = 0; j < 8; j++) acc += bf2f(v[j]) * ks[c8*8 + j];
    }
    acc += __shfl_down(acc, 4, 8);
    acc += __shfl_down(acc, 2, 8);
    acc += __shfl_down(acc, 1, 8);
    if (l8 == 0) z[b*NN + row] = 1.0f / (acc * 0.0625f + 16384.0f);
}

// ---------------- T6: final fused (q.kvT16, gate, Wo conv) ----------------
__global__ __launch_bounds__(256) void t6_final(const short* __restrict__ qkT, const short* __restrict__ kvT16,
    const short* __restrict__ yvg, const float* __restrict__ z,
    const float* __restrict__ Wo, const float* __restrict__ bo, float* __restrict__ out)
{
    int n0 = blockIdx.x * 64, b = blockIdx.y;
    __shared__ __align__(16) short Aq[64*40];
    __shared__ __align__(16) short Bw[256*40];
    __shared__ __align__(16) short S[64*264];
    int t = threadIdx.x, lane = t & 63, wid = t >> 6;
    int l15 = lane & 15, g = lane >> 4;

    f32x4 acc[4][4];
    #pragma unroll
    for (int i=0;i<4;i++)
        #pragma unroll
        for (int j=0;j<4;j++){ acc[i][j][0]=0.f; acc[i][j][1]=0.f; acc[i][j][2]=0.f; acc[i][j][3]=0.f; }

    const short* qb = qkT + (size_t)(b*NN + n0)*512;

    // GEMM-a: t[n][d] = sum_c q[n][c] * kvT16[d][c]
    for (int k0 = 0; k0 < 256; k0 += 32){
        __syncthreads();
        { int r = t >> 2, c8 = t & 3;
          *(bf16x8*)(&Aq[r*40 + c8*8]) = *(const bf16x8*)(qb + (size_t)r*512 + k0 + c8*8); }
        #pragma unroll
        for (int i = 0; i < 4; i++){
            int idx = i*256 + t;
            int r = idx >> 2, c8 = idx & 3;
            *(bf16x8*)(&Bw[r*40 + c8*8]) = *(const bf16x8*)(kvT16 + ((size_t)b*Cc + r)*Cc + k0 + c8*8);
        }
        __syncthreads();
        bf16x8 bfr[4];
        #pragma unroll
        for (int ni = 0; ni < 4; ni++) bfr[ni] = *(const bf16x8*)(&Bw[(wid*64 + ni*16 + l15)*40 + g*8]);
        #pragma unroll
        for (int mi = 0; mi < 4; mi++){
            bf16x8 a = *(const bf16x8*)(&Aq[(mi*16 + l15)*40 + g*8]);
            #pragma unroll
            for (int ni = 0; ni < 4; ni++)
                acc[mi][ni] = __builtin_amdgcn_mfma_f32_16x16x32_bf16(a, bfr[ni], acc[mi][ni], 0, 0, 0);
        }
    }
    // epilogue-a: s = (t + v) * z * g  -> S[n][d]
    #pragma unroll
    for (int mi = 0; mi < 4; mi++)
        #pragma unroll
        for (int r = 0; r < 4; r++){
            int nl = mi*16 + g*4 + r;
            float zv = z[b*NN + n0 + nl];
            const short* vrow = yvg + (size_t)(b*NN + n0 + nl)*512;
            #pragma unroll
            for (int ni = 0; ni < 4; ni++){
                int d = wid*64 + ni*16 + l15;
                float vv = bf2f(vrow[d]);
                float gg = bf2f(vrow[256 + d]);
                S[nl*264 + d] = f2bf((acc[mi][ni][r] + vv) * zv * gg);
            }
        }
    __syncthreads();

    // GEMM-b: out[o][n] = sum_d Wo[o][d] * S[n][d] + bo
    f32x4 acc2[4][4];
    #pragma unroll
    for (int i=0;i<4;i++)
        #pragma unroll
        for (int j=0;j<4;j++){ acc2[i][j][0]=0.f; acc2[i][j][1]=0.f; acc2[i][j][2]=0.f; acc2[i][j][3]=0.f; }

    for (int k0 = 0; k0 < 256; k0 += 32){
        __syncthreads();
        #pragma unroll
        for (int i = 0; i < 8; i++){
            int idx = i*256 + t;
            int r = idx >> 3, c4 = idx & 7;
            float4 v = *(const float4*)(Wo + (size_t)r*Cc + k0 + c4*4);
            bf16x4 pk = { f2bf(v.x), f2bf(v.y), f2bf(v.z), f2bf(v.w) };
            *(bf16x4*)(&Bw[r*40 + c4*4]) = pk;
        }
        __syncthreads();
        bf16x8 sfr[4];
        #pragma unroll
        for (int ni = 0; ni < 4; ni++) sfr[ni] = *(const bf16x8*)(&S[(ni*16 + l15)*264 + k0 + g*8]);
        #pragma unroll
        for (int mi = 0; mi < 4; mi++){
            bf16x8 a = *(const bf16x8*)(&Bw[(wid*64 + mi*16 + l15)*40 + g*8]);
            #pragma unroll
            for (int ni = 0; ni < 4; ni++)
                acc2[mi][ni] = __builtin_amdgcn_mfma_f32_16x16x32_bf16(a, sfr[ni], acc2[mi][ni], 0, 0, 0);
        }
    }
    #pragma unroll
    for (int mi = 0; mi < 4; mi++)
        #pragma unroll
        for (int ni = 0; ni < 4; ni++){
            int n = n0 + ni*16 + l15;
            #pragma unroll
            for (int r = 0; r < 4; r++){
                int o = wid*64 + mi*16 + g*4 + r;
                out[((size_t)b*Cc + o)*NN + n] = acc2[mi][ni][r] + bo[o];
            }
        }
}

// ---------------- host ----------------
extern "C" void kernel_launch(void* const* d_in, const int* in_sizes, int n_in,
                              void* d_out, int out_size, void* d_ws, size_t ws_size,
                              hipStream_t stream)
{
    (void)in_sizes; (void)n_in; (void)out_size; (void)ws_size;
    const float* x   = (const float*)d_in[0];
    const float* Wq1 = (const float*)d_in[1];
    const float* bq1 = (const float*)d_in[2];
    const float* Wq2 = (const float*)d_in[3];
    const float* bq2 = (const float*)d_in[4];
    const float* Wk1 = (const float*)d_in[5];
    const float* bk1 = (const float*)d_in[6];
    const float* Wk2 = (const float*)d_in[7];
    const float* bk2 = (const float*)d_in[8];
    const float* Wv  = (const float*)d_in[9];
    const float* bv  = (const float*)d_in[10];
    const float* Wg  = (const float*)d_in[11];
    const float* bg  = (const float*)d_in[12];
    const float* Wo  = (const float*)d_in[13];
    const float* bo  = (const float*)d_in[14];
    float* out = (float*)d_out;

    char* ws = (char*)d_ws;
    // workspace layout (bytes)
    float* mu    = (float*)(ws + 0);                       //   4 KB
    float* rstd  = (float*)(ws + 4096);                    //   4 KB
    float* kv    = (float*)(ws + 8192);                    //   1 MB  (memset 0)
    float* ksum  = (float*)(ws + 8192 + 1048576);          //   4 KB  (memset 0)
    float* z     = (float*)(ws + 1060864);                 // 256 KB
    short* kvT16 = (short*)(ws + 1323008);                 // 512 KB
    short* xnT   = (short*)(ws + 1851392);                 //  32 MB
    short* y1qk  = (short*)(ws + 1851392 + 33554432);      //  64 MB (off 35405824)
    short* yvg   = (short*)(ws + 35405824 + 67108864);     //  64 MB (off 102514688)
    short* qkT   = (short*)(ws + 102514688 + 67108864);    //  64 MB (off 169623552, end 236732416)
    short* kC    = xnT;                                    //  32 MB (xnT dead after T2)
    short* vC    = y1qk;                                   //  32 MB (y1qk dead after T3)

    hipMemsetAsync(ws + 8192, 0, 1048576 + 4096, stream);  // kv + ksum accumulators

    t0_stats     <<<dim3(1024),       256, 0, stream>>>(x, mu, rstd);
    t1_xnT       <<<dim3(256, 4, 4),  256, 0, stream>>>(x, mu, rstd, xnT);
    t2_conv1     <<<dim3(128, 8, 4),  256, 0, stream>>>(xnT, Wq1, bq1, Wk1, bk1, Wv, bv, Wg, bg, y1qk, yvg);
    t3_conv2     <<<dim3(128, 4, 4),  256, 0, stream>>>(y1qk, Wq2, bq2, Wk2, bk2, qkT, ksum);
    t3t_transpose<<<dim3(256, 4, 8),  256, 0, stream>>>(qkT, yvg, kC, vC);
    t4_kv        <<<dim3(2, 2, 128),  256, 0, stream>>>(kC, vC, kv);
    t4c_kvT      <<<dim3(256, 4),     256, 0, stream>>>(kv, kvT16);
    t5_z         <<<dim3(512, 4),     256, 0, stream>>>(qkT, ksum, z);
    t6_final     <<<dim3(256, 4),     256, 0, stream>>>(qkT, kvT16, yvg, z, Wo, bo, out);
}

// Round 4
// 430.743 us; speedup vs baseline: 1.4464x; 1.4464x over previous
//
#include <hip/hip_runtime.h>
#include <cstdint>
#include <cstddef>

// ---------------------------------------------------------------------------
// GAttn round 3: attack the measured VALU bound (t3: MfmaUtil 3.7%, VALUBusy 67%).
//   - tw: one-shot fp32->bf16 weight conversion (kills per-tile f2bf repack)
//   - fast softplus (native v_exp/v_log) replaces ocml log1pf
//   - fast gelu (A&S erf poly) replaces ocml erff
// Pipeline otherwise identical to round 2 (passed, absmax 2.4e-4):
//   T0 stats | T1 xnT | T2 conv1 | T3 conv2+ksum | T3t transpose | T4 kv
//   T4c kvT | T5 z | T6 final fused
// ---------------------------------------------------------------------------

#define DI __device__ __forceinline__

typedef __attribute__((ext_vector_type(8))) short bf16x8;
typedef __attribute__((ext_vector_type(4))) short bf16x4;
typedef __attribute__((ext_vector_type(4))) float f32x4;

static constexpr int Cc = 256;
static constexpr int NN = 16384;

DI float bf2f(short s){ unsigned int u = ((unsigned int)(unsigned short)s) << 16; float f; __builtin_memcpy(&f, &u, 4); return f; }
DI short f2bf(float f){ unsigned int u; __builtin_memcpy(&u, &f, 4); u += 0x7fffu + ((u >> 16) & 1u); return (short)(u >> 16); }

// gelu(x) = 0.5x(1+erf(x/sqrt2)); erf via A&S 7.1.26, |abs err| < 1.5e-7
DI float geluf(float x){
    float zz = x * 0.70710678118654752f;
    float az = fabsf(zz);
    float t  = __builtin_amdgcn_rcpf(fmaf(0.3275911f, az, 1.0f));
    float p  = fmaf(fmaf(fmaf(fmaf(1.061405429f, t, -1.453152027f), t,
                   1.421413741f), t, -0.284496736f), t, 0.254829592f) * t;
    float e  = __expf(-az * az);
    float er = copysignf(1.0f - p * e, zz);
    return 0.5f * x * (1.0f + er);
}
// softplus(x) = max(x,0) + log(1+exp(-|x|)); arg of log in (1,2] -> v_log accurate
DI float softplusf(float x){
    float e = __expf(-fabsf(x));
    return fmaxf(x, 0.0f) + __logf(1.0f + e);
}

// ---------------- TW: one-shot weight fp32->bf16 ----------------
__global__ __launch_bounds__(256) void tw_conv(
    const float* __restrict__ W0, const float* __restrict__ W1,
    const float* __restrict__ W2, const float* __restrict__ W3,
    const float* __restrict__ W4, const float* __restrict__ W5,
    const float* __restrict__ W6, short* __restrict__ dst)
{
    const float* srcs[7] = {W0, W1, W2, W3, W4, W5, W6};
    const float* W = srcs[blockIdx.y];
    short* d = dst + (size_t)blockIdx.y * 65536;
    int i = blockIdx.x * 256 + threadIdx.x;      // float4 index, 0..16383
    float4 v = *(const float4*)(W + (size_t)i * 4);
    bf16x4 pk = { f2bf(v.x), f2bf(v.y), f2bf(v.z), f2bf(v.w) };
    *(bf16x4*)(d + (size_t)i * 4) = pk;
}

// ---------------- T0: instance-norm stats ----------------
__global__ __launch_bounds__(256) void t0_stats(const float* __restrict__ x,
                                                float* __restrict__ mu, float* __restrict__ rstd)
{
    int row = blockIdx.x;                       // b*256 + c
    const float4* p = (const float4*)(x + (size_t)row * NN);
    float s = 0.f, ss = 0.f;
    for (int i = threadIdx.x; i < NN/4; i += 256){
        float4 v = p[i];
        s  += v.x + v.y + v.z + v.w;
        ss += v.x*v.x + v.y*v.y + v.z*v.z + v.w*v.w;
    }
    #pragma unroll
    for (int o = 32; o; o >>= 1){ s += __shfl_down(s, o); ss += __shfl_down(ss, o); }
    __shared__ float a0[4], a1[4];
    int w = threadIdx.x >> 6;
    if ((threadIdx.x & 63) == 0){ a0[w] = s; a1[w] = ss; }
    __syncthreads();
    if (threadIdx.x == 0){
        float S = a0[0]+a0[1]+a0[2]+a0[3], SS = a1[0]+a1[1]+a1[2]+a1[3];
        float m = S * (1.f/NN);
        float var = SS * (1.f/NN) - m*m;
        mu[row] = m;
        rstd[row] = rsqrtf(var + 1e-5f);
    }
}

// ---------------- T1: normalize + transpose -> xnT[b][n][c] ----------------
__global__ __launch_bounds__(256) void t1_xnT(const float* __restrict__ x,
                                              const float* __restrict__ mu, const float* __restrict__ rstd,
                                              short* __restrict__ xnT)
{
    int n0 = blockIdx.x * 64, c0 = blockIdx.y * 64, b = blockIdx.z;
    __shared__ __align__(16) short lds[64*72];
    int t = threadIdx.x;
    #pragma unroll
    for (int i = 0; i < 4; i++){
        int idx = i*256 + t;
        int c  = idx >> 4;          // 0..63
        int n4 = idx & 15;          // float4 along n
        int cg = b*Cc + c0 + c;
        float4 v = *(const float4*)(x + (size_t)cg*NN + n0 + n4*4);
        float m = mu[cg], rs = rstd[cg];
        int key = (c ^ (c >> 3)) & 7;
        int blk = (n4 >> 1) ^ key;
        bf16x4 pk = { f2bf((v.x-m)*rs), f2bf((v.y-m)*rs), f2bf((v.z-m)*rs), f2bf((v.w-m)*rs) };
        *(bf16x4*)(&lds[c*72 + blk*8 + (n4&1)*4]) = pk;
    }
    __syncthreads();
    #pragma unroll
    for (int i = 0; i < 2; i++){
        int idx = i*256 + t;
        int n  = idx >> 3;          // 0..63
        int c8 = idx & 7;
        bf16x8 pk;
        #pragma unroll
        for (int j = 0; j < 8; j++){
            int c = c8*8 + j;
            int key = (c ^ (c >> 3)) & 7;
            pk[j] = lds[c*72 + (((n >> 3) ^ key))*8 + (n & 7)];
        }
        *(bf16x8*)(xnT + ((size_t)(b*NN + n0 + n))*Cc + c0 + c8*8) = pk;
    }
}

// ---------------- T2: conv1 (4 branches, gelu) ----------------
__global__ __launch_bounds__(256) void t2_conv1(const short* __restrict__ xnT,
    const short* __restrict__ wbf,
    const float* __restrict__ bq1, const float* __restrict__ bk1,
    const float* __restrict__ bv,  const float* __restrict__ bg,
    short* __restrict__ y1qk, short* __restrict__ yvg)
{
    int n0 = blockIdx.x * 128;
    int stile = blockIdx.y;             // 0..7
    int b = blockIdx.z;
    int branch = stile >> 1;            // 0=Wq1 1=Wk1 2=Wv 3=Wg (wbf order)
    const short* wb = wbf + (size_t)branch * 65536;
    const float* bs = branch==0 ? bq1 : branch==1 ? bk1 : branch==2 ? bv : bg;
    int s0b = (stile & 1) * 128;
    short* dst; int dcol;
    if (stile < 4){ dst = y1qk; dcol = stile*128; } else { dst = yvg; dcol = (stile-4)*128; }

    __shared__ __align__(16) short Al[128*40];
    __shared__ __align__(16) short Bl[128*40];
    int t = threadIdx.x, lane = t & 63, wid = t >> 6;
    int wm = (wid & 1) * 64, wn = (wid >> 1) * 64;
    int l15 = lane & 15, g = lane >> 4;

    f32x4 acc[4][4];
    #pragma unroll
    for (int i=0;i<4;i++)
        #pragma unroll
        for (int j=0;j<4;j++){ acc[i][j][0]=0.f; acc[i][j][1]=0.f; acc[i][j][2]=0.f; acc[i][j][3]=0.f; }

    const short* xb = xnT + (size_t)(b*NN + n0) * Cc;

    for (int k0 = 0; k0 < 256; k0 += 32){
        __syncthreads();
        #pragma unroll
        for (int i = 0; i < 2; i++){            // A: xnT 128n x 32c
            int idx = i*256 + t;
            int r = idx >> 2, c8 = idx & 3;
            *(bf16x8*)(&Al[r*40 + c8*8]) = *(const bf16x8*)(xb + (size_t)r*Cc + k0 + c8*8);
        }
        #pragma unroll
        for (int i = 0; i < 2; i++){            // B: W(bf16) 128s x 32c
            int idx = i*256 + t;
            int r = idx >> 2, c8 = idx & 3;
            *(bf16x8*)(&Bl[r*40 + c8*8]) = *(const bf16x8*)(wb + (size_t)(s0b + r)*Cc + k0 + c8*8);
        }
        __syncthreads();
        bf16x8 bfr[4];
        #pragma unroll
        for (int ni = 0; ni < 4; ni++) bfr[ni] = *(const bf16x8*)(&Bl[(wn + ni*16 + l15)*40 + g*8]);
        #pragma unroll
        for (int mi = 0; mi < 4; mi++){
            bf16x8 a = *(const bf16x8*)(&Al[(wm + mi*16 + l15)*40 + g*8]);
            #pragma unroll
            for (int ni = 0; ni < 4; ni++)
                acc[mi][ni] = __builtin_amdgcn_mfma_f32_16x16x32_bf16(a, bfr[ni], acc[mi][ni], 0, 0, 0);
        }
    }
    short* outb = dst + (size_t)(b*NN + n0) * 512 + dcol;
    #pragma unroll
    for (int mi = 0; mi < 4; mi++)
        #pragma unroll
        for (int ni = 0; ni < 4; ni++){
            int coll = wn + ni*16 + l15;
            float bias = bs[s0b + coll];
            #pragma unroll
            for (int r = 0; r < 4; r++){
                int row = wm + mi*16 + g*4 + r;
                outb[(size_t)row*512 + coll] = f2bf(geluf(acc[mi][ni][r] + bias));
            }
        }
}

// ---------------- T3: conv2 (q,k softplus) + ksum ----------------
__global__ __launch_bounds__(256) void t3_conv2(const short* __restrict__ y1qk,
    const short* __restrict__ wbf,
    const float* __restrict__ bq2, const float* __restrict__ bk2,
    short* __restrict__ qkT, float* __restrict__ ksum)
{
    int n0 = blockIdx.x * 128;
    int stile = blockIdx.y;             // 0..3
    int b = blockIdx.z;
    int branch = stile >> 1;            // 0=q, 1=k
    const short* wb = wbf + (size_t)(4 + branch) * 65536;   // Wq2 / Wk2
    const float* bs = branch ? bk2 : bq2;
    int ksrc = branch * 256;            // q1 at cols 0..255, k1 at 256..511
    int s0b = (stile & 1) * 128;

    __shared__ __align__(16) short Al[128*40];
    __shared__ __align__(16) short Bl[128*40];
    int t = threadIdx.x, lane = t & 63, wid = t >> 6;
    int wm = (wid & 1) * 64, wn = (wid >> 1) * 64;
    int l15 = lane & 15, g = lane >> 4;

    f32x4 acc[4][4];
    #pragma unroll
    for (int i=0;i<4;i++)
        #pragma unroll
        for (int j=0;j<4;j++){ acc[i][j][0]=0.f; acc[i][j][1]=0.f; acc[i][j][2]=0.f; acc[i][j][3]=0.f; }

    const short* src = y1qk + (size_t)(b*NN + n0) * 512 + ksrc;

    for (int k0 = 0; k0 < 256; k0 += 32){
        __syncthreads();
        #pragma unroll
        for (int i = 0; i < 2; i++){
            int idx = i*256 + t;
            int r = idx >> 2, c8 = idx & 3;
            *(bf16x8*)(&Al[r*40 + c8*8]) = *(const bf16x8*)(src + (size_t)r*512 + k0 + c8*8);
        }
        #pragma unroll
        for (int i = 0; i < 2; i++){
            int idx = i*256 + t;
            int r = idx >> 2, c8 = idx & 3;
            *(bf16x8*)(&Bl[r*40 + c8*8]) = *(const bf16x8*)(wb + (size_t)(s0b + r)*Cc + k0 + c8*8);
        }
        __syncthreads();
        bf16x8 bfr[4];
        #pragma unroll
        for (int ni = 0; ni < 4; ni++) bfr[ni] = *(const bf16x8*)(&Bl[(wn + ni*16 + l15)*40 + g*8]);
        #pragma unroll
        for (int mi = 0; mi < 4; mi++){
            bf16x8 a = *(const bf16x8*)(&Al[(wm + mi*16 + l15)*40 + g*8]);
            #pragma unroll
            for (int ni = 0; ni < 4; ni++)
                acc[mi][ni] = __builtin_amdgcn_mfma_f32_16x16x32_bf16(a, bfr[ni], acc[mi][ni], 0, 0, 0);
        }
    }
    short* outb = qkT + (size_t)(b*NN + n0) * 512 + branch*256 + s0b;
    float csum[4] = {0.f, 0.f, 0.f, 0.f};
    #pragma unroll
    for (int mi = 0; mi < 4; mi++)
        #pragma unroll
        for (int ni = 0; ni < 4; ni++){
            int coll = wn + ni*16 + l15;
            float bias = bs[s0b + coll];
            #pragma unroll
            for (int r = 0; r < 4; r++){
                int row = wm + mi*16 + g*4 + r;
                float val = softplusf(acc[mi][ni][r] + bias);
                outb[(size_t)row*512 + coll] = f2bf(val);
                csum[ni] += val;
            }
        }
    if (branch == 1){
        #pragma unroll
        for (int ni = 0; ni < 4; ni++){
            float v = csum[ni];
            v += __shfl_xor(v, 16);
            v += __shfl_xor(v, 32);
            if (g == 0) atomicAdd(&ksum[b*Cc + s0b + wn + ni*16 + l15], v);
        }
    }
}

// ---------------- T3t: transpose k,v to c-major ----------------
__global__ __launch_bounds__(256) void t3t_transpose(const short* __restrict__ qkT, const short* __restrict__ yvg,
                                                     short* __restrict__ kC, short* __restrict__ vC)
{
    int n0 = blockIdx.x * 64;
    int c0 = blockIdx.y * 64;
    int b  = blockIdx.z >> 1;
    int which = blockIdx.z & 1;
    const short* src; short* dst;
    if (which == 0){ src = qkT + (size_t)(b*NN + n0)*512 + 256 + c0; dst = kC + (size_t)(b*Cc + c0)*NN + n0; }
    else           { src = yvg + (size_t)(b*NN + n0)*512 +   0 + c0; dst = vC + (size_t)(b*Cc + c0)*NN + n0; }
    __shared__ __align__(16) short lds[64*72];
    int t = threadIdx.x;
    #pragma unroll
    for (int i = 0; i < 2; i++){
        int idx = i*256 + t;
        int n = idx >> 3, c8 = idx & 7;
        bf16x8 v = *(const bf16x8*)(src + (size_t)n*512 + c8*8);
        int key = (n ^ (n >> 3)) & 7;
        *(bf16x8*)(&lds[n*72 + (c8 ^ key)*8]) = v;
    }
    __syncthreads();
    #pragma unroll
    for (int i = 0; i < 2; i++){
        int idx = i*256 + t;
        int c = idx >> 3, n8 = idx & 7;
        bf16x8 pk;
        #pragma unroll
        for (int j = 0; j < 8; j++){
            int n = n8*8 + j;
            int key = (n ^ (n >> 3)) & 7;
            pk[j] = lds[n*72 + (((c >> 3) ^ key))*8 + (c & 7)];
        }
        *(bf16x8*)(dst + (size_t)c*NN + n8*8) = pk;
    }
}

// ---------------- T4: kv GEMM (atomic K-split) ----------------
__global__ __launch_bounds__(256) void t4_kv(const short* __restrict__ kC, const short* __restrict__ vC,
                                             float* __restrict__ kv)
{
    int m0 = blockIdx.x * 128;          // c
    int d0 = blockIdx.y * 128;          // d
    int b  = blockIdx.z >> 5;
    int nb = (blockIdx.z & 31) * 512;

    __shared__ __align__(16) short Al[128*40];
    __shared__ __align__(16) short Bl[128*40];
    int t = threadIdx.x, lane = t & 63, wid = t >> 6;
    int wm = (wid & 1) * 64, wn = (wid >> 1) * 64;
    int l15 = lane & 15, g = lane >> 4;

    f32x4 acc[4][4];
    #pragma unroll
    for (int i=0;i<4;i++)
        #pragma unroll
        for (int j=0;j<4;j++){ acc[i][j][0]=0.f; acc[i][j][1]=0.f; acc[i][j][2]=0.f; acc[i][j][3]=0.f; }

    const short* ka = kC + (size_t)(b*Cc + m0)*NN + nb;
    const short* vb = vC + (size_t)(b*Cc + d0)*NN + nb;

    for (int k0 = 0; k0 < 512; k0 += 32){
        __syncthreads();
        #pragma unroll
        for (int i = 0; i < 2; i++){
            int idx = i*256 + t;
            int r = idx >> 2, c8 = idx & 3;
            *(bf16x8*)(&Al[r*40 + c8*8]) = *(const bf16x8*)(ka + (size_t)r*NN + k0 + c8*8);
            *(bf16x8*)(&Bl[r*40 + c8*8]) = *(const bf16x8*)(vb + (size_t)r*NN + k0 + c8*8);
        }
        __syncthreads();
        bf16x8 bfr[4];
        #pragma unroll
        for (int ni = 0; ni < 4; ni++) bfr[ni] = *(const bf16x8*)(&Bl[(wn + ni*16 + l15)*40 + g*8]);
        #pragma unroll
        for (int mi = 0; mi < 4; mi++){
            bf16x8 a = *(const bf16x8*)(&Al[(wm + mi*16 + l15)*40 + g*8]);
            #pragma unroll
            for (int ni = 0; ni < 4; ni++)
                acc[mi][ni] = __builtin_amdgcn_mfma_f32_16x16x32_bf16(a, bfr[ni], acc[mi][ni], 0, 0, 0);
        }
    }
    #pragma unroll
    for (int mi = 0; mi < 4; mi++)
        #pragma unroll
        for (int ni = 0; ni < 4; ni++){
            int coll = wn + ni*16 + l15;
            #pragma unroll
            for (int r = 0; r < 4; r++){
                int row = wm + mi*16 + g*4 + r;
                atomicAdd(&kv[((size_t)b*Cc + m0 + row)*Cc + d0 + coll], acc[mi][ni][r]);
            }
        }
}

// ---------------- T4c: kvT16[d][c] = bf16(kv[c][d]/16) ----------------
__global__ __launch_bounds__(256) void t4c_kvT(const float* __restrict__ kv, short* __restrict__ kvT16)
{
    int d = blockIdx.x, b = blockIdx.y, c = threadIdx.x;
    float v = kv[((size_t)b*Cc + c)*Cc + d] * 0.0625f;
    kvT16[((size_t)b*Cc + d)*Cc + c] = f2bf(v);
}

// ---------------- T5: z = 1/(q.ksum/16 + N) ----------------
__global__ __launch_bounds__(256) void t5_z(const short* __restrict__ qkT, const float* __restrict__ ksum,
                                            float* __restrict__ z)
{
    int b = blockIdx.y;
    int n0 = blockIdx.x * 32;
    __shared__ float ks[256];
    int t = threadIdx.x;
    ks[t] = ksum[b*Cc + t];
    __syncthreads();
    int row = n0 + (t >> 3), l8 = t & 7;
    const short* q = qkT + (size_t)(b*NN + row)*512;
    float acc = 0.f;
    #pragma unroll
    for (int i = 0; i < 4; i++){
        int c8 = i*8 + l8;
        bf16x8 v = *(const bf16x8*)(q + c8*8);
        #pragma unroll
        for (int j = 0; j < 8; j++) acc += bf2f(v[j]) * ks[c8*8 + j];
    }
    acc += __shfl_down(acc, 4, 8);
    acc += __shfl_down(acc, 2, 8);
    acc += __shfl_down(acc, 1, 8);
    if (l8 == 0) z[b*NN + row] = 1.0f / (acc * 0.0625f + 16384.0f);
}

// ---------------- T6: final fused (q.kvT16, gate, Wo conv) ----------------
__global__ __launch_bounds__(256) void t6_final(const short* __restrict__ qkT, const short* __restrict__ kvT16,
    const short* __restrict__ yvg, const float* __restrict__ z,
    const short* __restrict__ wbf, const float* __restrict__ bo, float* __restrict__ out)
{
    int n0 = blockIdx.x * 64, b = blockIdx.y;
    __shared__ __align__(16) short Aq[64*40];
    __shared__ __align__(16) short Bw[256*40];
    __shared__ __align__(16) short S[64*264];
    int t = threadIdx.x, lane = t & 63, wid = t >> 6;
    int l15 = lane & 15, g = lane >> 4;
    const short* wo_bf = wbf + (size_t)6 * 65536;

    f32x4 acc[4][4];
    #pragma unroll
    for (int i=0;i<4;i++)
        #pragma unroll
        for (int j=0;j<4;j++){ acc[i][j][0]=0.f; acc[i][j][1]=0.f; acc[i][j][2]=0.f; acc[i][j][3]=0.f; }

    const short* qb = qkT + (size_t)(b*NN + n0)*512;

    // GEMM-a: t[n][d] = sum_c q[n][c] * kvT16[d][c]
    for (int k0 = 0; k0 < 256; k0 += 32){
        __syncthreads();
        { int r = t >> 2, c8 = t & 3;
          *(bf16x8*)(&Aq[r*40 + c8*8]) = *(const bf16x8*)(qb + (size_t)r*512 + k0 + c8*8); }
        #pragma unroll
        for (int i = 0; i < 4; i++){
            int idx = i*256 + t;
            int r = idx >> 2, c8 = idx & 3;
            *(bf16x8*)(&Bw[r*40 + c8*8]) = *(const bf16x8*)(kvT16 + ((size_t)b*Cc + r)*Cc + k0 + c8*8);
        }
        __syncthreads();
        bf16x8 bfr[4];
        #pragma unroll
        for (int ni = 0; ni < 4; ni++) bfr[ni] = *(const bf16x8*)(&Bw[(wid*64 + ni*16 + l15)*40 + g*8]);
        #pragma unroll
        for (int mi = 0; mi < 4; mi++){
            bf16x8 a = *(const bf16x8*)(&Aq[(mi*16 + l15)*40 + g*8]);
            #pragma unroll
            for (int ni = 0; ni < 4; ni++)
                acc[mi][ni] = __builtin_amdgcn_mfma_f32_16x16x32_bf16(a, bfr[ni], acc[mi][ni], 0, 0, 0);
        }
    }
    // epilogue-a: s = (t + v) * z * g  -> S[n][d]
    #pragma unroll
    for (int mi = 0; mi < 4; mi++)
        #pragma unroll
        for (int r = 0; r < 4; r++){
            int nl = mi*16 + g*4 + r;
            float zv = z[b*NN + n0 + nl];
            const short* vrow = yvg + (size_t)(b*NN + n0 + nl)*512;
            #pragma unroll
            for (int ni = 0; ni < 4; ni++){
                int d = wid*64 + ni*16 + l15;
                float vv = bf2f(vrow[d]);
                float gg = bf2f(vrow[256 + d]);
                S[nl*264 + d] = f2bf((acc[mi][ni][r] + vv) * zv * gg);
            }
        }
    __syncthreads();

    // GEMM-b: out[o][n] = sum_d Wo[o][d] * S[n][d] + bo
    f32x4 acc2[4][4];
    #pragma unroll
    for (int i=0;i<4;i++)
        #pragma unroll
        for (int j=0;j<4;j++){ acc2[i][j][0]=0.f; acc2[i][j][1]=0.f; acc2[i][j][2]=0.f; acc2[i][j][3]=0.f; }

    for (int k0 = 0; k0 < 256; k0 += 32){
        __syncthreads();
        #pragma unroll
        for (int i = 0; i < 4; i++){            // Wo(bf16) 256 x 32
            int idx = i*256 + t;
            int r = idx >> 2, c8 = idx & 3;
            *(bf16x8*)(&Bw[r*40 + c8*8]) = *(const bf16x8*)(wo_bf + (size_t)r*Cc + k0 + c8*8);
        }
        __syncthreads();
        bf16x8 sfr[4];
        #pragma unroll
        for (int ni = 0; ni < 4; ni++) sfr[ni] = *(const bf16x8*)(&S[(ni*16 + l15)*264 + k0 + g*8]);
        #pragma unroll
        for (int mi = 0; mi < 4; mi++){
            bf16x8 a = *(const bf16x8*)(&Bw[(wid*64 + mi*16 + l15)*40 + g*8]);
            #pragma unroll
            for (int ni = 0; ni < 4; ni++)
                acc2[mi][ni] = __builtin_amdgcn_mfma_f32_16x16x32_bf16(a, sfr[ni], acc2[mi][ni], 0, 0, 0);
        }
    }
    #pragma unroll
    for (int mi = 0; mi < 4; mi++)
        #pragma unroll
        for (int ni = 0; ni < 4; ni++){
            int n = n0 + ni*16 + l15;
            #pragma unroll
            for (int r = 0; r < 4; r++){
                int o = wid*64 + mi*16 + g*4 + r;
                out[((size_t)b*Cc + o)*NN + n] = acc2[mi][ni][r] + bo[o];
            }
        }
}

// ---------------- host ----------------
extern "C" void kernel_launch(void* const* d_in, const int* in_sizes, int n_in,
                              void* d_out, int out_size, void* d_ws, size_t ws_size,
                              hipStream_t stream)
{
    (void)in_sizes; (void)n_in; (void)out_size; (void)ws_size;
    const float* x   = (const float*)d_in[0];
    const float* Wq1 = (const float*)d_in[1];
    const float* bq1 = (const float*)d_in[2];
    const float* Wq2 = (const float*)d_in[3];
    const float* bq2 = (const float*)d_in[4];
    const float* Wk1 = (const float*)d_in[5];
    const float* bk1 = (const float*)d_in[6];
    const float* Wk2 = (const float*)d_in[7];
    const float* bk2 = (const float*)d_in[8];
    const float* Wv  = (const float*)d_in[9];
    const float* bv  = (const float*)d_in[10];
    const float* Wg  = (const float*)d_in[11];
    const float* bg  = (const float*)d_in[12];
    const float* Wo  = (const float*)d_in[13];
    const float* bo  = (const float*)d_in[14];
    float* out = (float*)d_out;

    char* ws = (char*)d_ws;
    // workspace layout (bytes)
    float* mu    = (float*)(ws + 0);                //   4 KB
    float* rstd  = (float*)(ws + 4096);             //   4 KB
    float* z     = (float*)(ws + 8192);             // 256 KB  (ends 270336)
    short* kvT16 = (short*)(ws + 270336);           // 512 KB  (ends 794624)
    short* wbf   = (short*)(ws + 794624);           // 896 KB  bf16 weights (ends 1712128)
    float* ksum  = (float*)(ws + 1712128);          //   4 KB  (memset 0)
    float* kv    = (float*)(ws + 1716224);          //   1 MB  (memset 0, ends 2764800)
    short* xnT   = (short*)(ws + 3145728);          //  32 MB  (ends 36700160)
    short* y1qk  = (short*)(ws + 36700160);         //  64 MB  (ends 103809024)
    short* yvg   = (short*)(ws + 103809024);        //  64 MB  (ends 170917888)
    short* qkT   = (short*)(ws + 170917888);        //  64 MB  (ends 238026752)
    short* kC    = xnT;                             //  32 MB  (xnT dead after T2)
    short* vC    = y1qk;                            //  32 MB  (y1qk dead after T3)

    hipMemsetAsync(ws + 1712128, 0, 4096 + 1048576, stream);   // ksum + kv

    tw_conv      <<<dim3(64, 7),      256, 0, stream>>>(Wq1, Wk1, Wv, Wg, Wq2, Wk2, Wo, wbf);
    t0_stats     <<<dim3(1024),       256, 0, stream>>>(x, mu, rstd);
    t1_xnT       <<<dim3(256, 4, 4),  256, 0, stream>>>(x, mu, rstd, xnT);
    t2_conv1     <<<dim3(128, 8, 4),  256, 0, stream>>>(xnT, wbf, bq1, bk1, bv, bg, y1qk, yvg);
    t3_conv2     <<<dim3(128, 4, 4),  256, 0, stream>>>(y1qk, wbf, bq2, bk2, qkT, ksum);
    t3t_transpose<<<dim3(256, 4, 8),  256, 0, stream>>>(qkT, yvg, kC, vC);
    t4_kv        <<<dim3(2, 2, 128),  256, 0, stream>>>(kC, vC, kv);
    t4c_kvT      <<<dim3(256, 4),     256, 0, stream>>>(kv, kvT16);
    t5_z         <<<dim3(512, 4),     256, 0, stream>>>(qkT, ksum, z);
    t6_final     <<<dim3(256, 4),     256, 0, stream>>>(qkT, kvT16, yvg, z, wbf, bo, out);
}

// Round 5
// 409.988 us; speedup vs baseline: 1.5196x; 1.0506x over previous
//
#include <hip/hip_runtime.h>
#include <cstdint>
#include <cstddef>

// ---------------------------------------------------------------------------
// GAttn round 4: global_load_lds staging (m97 pattern) in all MFMA kernels.
//   t2/t3/t4/t6: unpadded [rows][32] LDS tiles, width-16 global_load_lds,
//   per-lane global addr carries the layout (LDS dest linear, m104/m173).
// Rest identical to round 3 (passed 430 µs, absmax 2.4e-4).
// ---------------------------------------------------------------------------

#define DI __device__ __forceinline__

typedef __attribute__((ext_vector_type(8))) short bf16x8;
typedef __attribute__((ext_vector_type(4))) short bf16x4;
typedef __attribute__((ext_vector_type(4))) float f32x4;

static constexpr int Cc = 256;
static constexpr int NN = 16384;

DI float bf2f(short s){ unsigned int u = ((unsigned int)(unsigned short)s) << 16; float f; __builtin_memcpy(&f, &u, 4); return f; }
DI short f2bf(float f){ unsigned int u; __builtin_memcpy(&u, &f, 4); u += 0x7fffu + ((u >> 16) & 1u); return (short)(u >> 16); }

typedef __attribute__((address_space(1))) const unsigned int gu32;
typedef __attribute__((address_space(3))) unsigned int lu32;
DI void gload16(const short* g, short* l){
    __builtin_amdgcn_global_load_lds((gu32*)g, (lu32*)l, 16, 0, 0);
}

// gelu(x) = 0.5x(1+erf(x/sqrt2)); erf via A&S 7.1.26, |abs err| < 1.5e-7
DI float geluf(float x){
    float zz = x * 0.70710678118654752f;
    float az = fabsf(zz);
    float t  = __builtin_amdgcn_rcpf(fmaf(0.3275911f, az, 1.0f));
    float p  = fmaf(fmaf(fmaf(fmaf(1.061405429f, t, -1.453152027f), t,
                   1.421413741f), t, -0.284496736f), t, 0.254829592f) * t;
    float e  = __expf(-az * az);
    float er = copysignf(1.0f - p * e, zz);
    return 0.5f * x * (1.0f + er);
}
// softplus(x) = max(x,0) + log(1+exp(-|x|)); log arg in (1,2] -> v_log accurate
DI float softplusf(float x){
    float e = __expf(-fabsf(x));
    return fmaxf(x, 0.0f) + __logf(1.0f + e);
}

// ---------------- TW: one-shot weight fp32->bf16 ----------------
__global__ __launch_bounds__(256) void tw_conv(
    const float* __restrict__ W0, const float* __restrict__ W1,
    const float* __restrict__ W2, const float* __restrict__ W3,
    const float* __restrict__ W4, const float* __restrict__ W5,
    const float* __restrict__ W6, short* __restrict__ dst)
{
    const float* srcs[7] = {W0, W1, W2, W3, W4, W5, W6};
    const float* W = srcs[blockIdx.y];
    short* d = dst + (size_t)blockIdx.y * 65536;
    int i = blockIdx.x * 256 + threadIdx.x;
    float4 v = *(const float4*)(W + (size_t)i * 4);
    bf16x4 pk = { f2bf(v.x), f2bf(v.y), f2bf(v.z), f2bf(v.w) };
    *(bf16x4*)(d + (size_t)i * 4) = pk;
}

// ---------------- T0: instance-norm stats ----------------
__global__ __launch_bounds__(256) void t0_stats(const float* __restrict__ x,
                                                float* __restrict__ mu, float* __restrict__ rstd)
{
    int row = blockIdx.x;
    const float4* p = (const float4*)(x + (size_t)row * NN);
    float s = 0.f, ss = 0.f;
    for (int i = threadIdx.x; i < NN/4; i += 256){
        float4 v = p[i];
        s  += v.x + v.y + v.z + v.w;
        ss += v.x*v.x + v.y*v.y + v.z*v.z + v.w*v.w;
    }
    #pragma unroll
    for (int o = 32; o; o >>= 1){ s += __shfl_down(s, o); ss += __shfl_down(ss, o); }
    __shared__ float a0[4], a1[4];
    int w = threadIdx.x >> 6;
    if ((threadIdx.x & 63) == 0){ a0[w] = s; a1[w] = ss; }
    __syncthreads();
    if (threadIdx.x == 0){
        float S = a0[0]+a0[1]+a0[2]+a0[3], SS = a1[0]+a1[1]+a1[2]+a1[3];
        float m = S * (1.f/NN);
        float var = SS * (1.f/NN) - m*m;
        mu[row] = m;
        rstd[row] = rsqrtf(var + 1e-5f);
    }
}

// ---------------- T1: normalize + transpose -> xnT[b][n][c] ----------------
__global__ __launch_bounds__(256) void t1_xnT(const float* __restrict__ x,
                                              const float* __restrict__ mu, const float* __restrict__ rstd,
                                              short* __restrict__ xnT)
{
    int n0 = blockIdx.x * 64, c0 = blockIdx.y * 64, b = blockIdx.z;
    __shared__ __align__(16) short lds[64*72];
    int t = threadIdx.x;
    #pragma unroll
    for (int i = 0; i < 4; i++){
        int idx = i*256 + t;
        int c  = idx >> 4;
        int n4 = idx & 15;
        int cg = b*Cc + c0 + c;
        float4 v = *(const float4*)(x + (size_t)cg*NN + n0 + n4*4);
        float m = mu[cg], rs = rstd[cg];
        int key = (c ^ (c >> 3)) & 7;
        int blk = (n4 >> 1) ^ key;
        bf16x4 pk = { f2bf((v.x-m)*rs), f2bf((v.y-m)*rs), f2bf((v.z-m)*rs), f2bf((v.w-m)*rs) };
        *(bf16x4*)(&lds[c*72 + blk*8 + (n4&1)*4]) = pk;
    }
    __syncthreads();
    #pragma unroll
    for (int i = 0; i < 2; i++){
        int idx = i*256 + t;
        int n  = idx >> 3;
        int c8 = idx & 7;
        bf16x8 pk;
        #pragma unroll
        for (int j = 0; j < 8; j++){
            int c = c8*8 + j;
            int key = (c ^ (c >> 3)) & 7;
            pk[j] = lds[c*72 + (((n >> 3) ^ key))*8 + (n & 7)];
        }
        *(bf16x8*)(xnT + ((size_t)(b*NN + n0 + n))*Cc + c0 + c8*8) = pk;
    }
}

// ---------------- T2: conv1 (4 branches, gelu) ----------------
__global__ __launch_bounds__(256) void t2_conv1(const short* __restrict__ xnT,
    const short* __restrict__ wbf,
    const float* __restrict__ bq1, const float* __restrict__ bk1,
    const float* __restrict__ bv,  const float* __restrict__ bg,
    short* __restrict__ y1qk, short* __restrict__ yvg)
{
    int n0 = blockIdx.x * 128;
    int stile = blockIdx.y;             // 0..7
    int b = blockIdx.z;
    int branch = stile >> 1;            // 0=Wq1 1=Wk1 2=Wv 3=Wg
    const short* wb = wbf + (size_t)branch * 65536;
    const float* bs = branch==0 ? bq1 : branch==1 ? bk1 : branch==2 ? bv : bg;
    int s0b = (stile & 1) * 128;
    short* dst; int dcol;
    if (stile < 4){ dst = y1qk; dcol = stile*128; } else { dst = yvg; dcol = (stile-4)*128; }

    __shared__ __align__(16) short Al[128*32];
    __shared__ __align__(16) short Bl[128*32];
    int t = threadIdx.x, lane = t & 63, wid = t >> 6;
    int wm = (wid & 1) * 64, wn = (wid >> 1) * 64;
    int l15 = lane & 15, g = lane >> 4;
    // gload geometry: lds short off = i*2048 + wid*512 + lane*8
    int srow = wid*16 + (lane >> 2);        // + i*64
    int scol = (lane & 3) * 8;
    int sdst = wid*512 + lane*8;            // + i*2048

    f32x4 acc[4][4];
    #pragma unroll
    for (int i=0;i<4;i++)
        #pragma unroll
        for (int j=0;j<4;j++){ acc[i][j][0]=0.f; acc[i][j][1]=0.f; acc[i][j][2]=0.f; acc[i][j][3]=0.f; }

    const short* xb = xnT + (size_t)(b*NN + n0) * Cc;

    for (int k0 = 0; k0 < 256; k0 += 32){
        __syncthreads();
        #pragma unroll
        for (int i = 0; i < 2; i++){
            gload16(xb + (size_t)(i*64 + srow)*Cc + k0 + scol, &Al[i*2048 + sdst]);
            gload16(wb + (size_t)(s0b + i*64 + srow)*Cc + k0 + scol, &Bl[i*2048 + sdst]);
        }
        __syncthreads();
        bf16x8 bfr[4];
        #pragma unroll
        for (int ni = 0; ni < 4; ni++) bfr[ni] = *(const bf16x8*)(&Bl[(wn + ni*16 + l15)*32 + g*8]);
        #pragma unroll
        for (int mi = 0; mi < 4; mi++){
            bf16x8 a = *(const bf16x8*)(&Al[(wm + mi*16 + l15)*32 + g*8]);
            #pragma unroll
            for (int ni = 0; ni < 4; ni++)
                acc[mi][ni] = __builtin_amdgcn_mfma_f32_16x16x32_bf16(a, bfr[ni], acc[mi][ni], 0, 0, 0);
        }
    }
    short* outb = dst + (size_t)(b*NN + n0) * 512 + dcol;
    #pragma unroll
    for (int mi = 0; mi < 4; mi++)
        #pragma unroll
        for (int ni = 0; ni < 4; ni++){
            int coll = wn + ni*16 + l15;
            float bias = bs[s0b + coll];
            #pragma unroll
            for (int r = 0; r < 4; r++){
                int row = wm + mi*16 + g*4 + r;
                outb[(size_t)row*512 + coll] = f2bf(geluf(acc[mi][ni][r] + bias));
            }
        }
}

// ---------------- T3: conv2 (q,k softplus) + ksum ----------------
__global__ __launch_bounds__(256) void t3_conv2(const short* __restrict__ y1qk,
    const short* __restrict__ wbf,
    const float* __restrict__ bq2, const float* __restrict__ bk2,
    short* __restrict__ qkT, float* __restrict__ ksum)
{
    int n0 = blockIdx.x * 128;
    int stile = blockIdx.y;             // 0..3
    int b = blockIdx.z;
    int branch = stile >> 1;            // 0=q, 1=k
    const short* wb = wbf + (size_t)(4 + branch) * 65536;
    const float* bs = branch ? bk2 : bq2;
    int ksrc = branch * 256;
    int s0b = (stile & 1) * 128;

    __shared__ __align__(16) short Al[128*32];
    __shared__ __align__(16) short Bl[128*32];
    int t = threadIdx.x, lane = t & 63, wid = t >> 6;
    int wm = (wid & 1) * 64, wn = (wid >> 1) * 64;
    int l15 = lane & 15, g = lane >> 4;
    int srow = wid*16 + (lane >> 2);
    int scol = (lane & 3) * 8;
    int sdst = wid*512 + lane*8;

    f32x4 acc[4][4];
    #pragma unroll
    for (int i=0;i<4;i++)
        #pragma unroll
        for (int j=0;j<4;j++){ acc[i][j][0]=0.f; acc[i][j][1]=0.f; acc[i][j][2]=0.f; acc[i][j][3]=0.f; }

    const short* src = y1qk + (size_t)(b*NN + n0) * 512 + ksrc;

    for (int k0 = 0; k0 < 256; k0 += 32){
        __syncthreads();
        #pragma unroll
        for (int i = 0; i < 2; i++){
            gload16(src + (size_t)(i*64 + srow)*512 + k0 + scol, &Al[i*2048 + sdst]);
            gload16(wb + (size_t)(s0b + i*64 + srow)*Cc + k0 + scol, &Bl[i*2048 + sdst]);
        }
        __syncthreads();
        bf16x8 bfr[4];
        #pragma unroll
        for (int ni = 0; ni < 4; ni++) bfr[ni] = *(const bf16x8*)(&Bl[(wn + ni*16 + l15)*32 + g*8]);
        #pragma unroll
        for (int mi = 0; mi < 4; mi++){
            bf16x8 a = *(const bf16x8*)(&Al[(wm + mi*16 + l15)*32 + g*8]);
            #pragma unroll
            for (int ni = 0; ni < 4; ni++)
                acc[mi][ni] = __builtin_amdgcn_mfma_f32_16x16x32_bf16(a, bfr[ni], acc[mi][ni], 0, 0, 0);
        }
    }
    short* outb = qkT + (size_t)(b*NN + n0) * 512 + branch*256 + s0b;
    float csum[4] = {0.f, 0.f, 0.f, 0.f};
    #pragma unroll
    for (int mi = 0; mi < 4; mi++)
        #pragma unroll
        for (int ni = 0; ni < 4; ni++){
            int coll = wn + ni*16 + l15;
            float bias = bs[s0b + coll];
            #pragma unroll
            for (int r = 0; r < 4; r++){
                int row = wm + mi*16 + g*4 + r;
                float val = softplusf(acc[mi][ni][r] + bias);
                outb[(size_t)row*512 + coll] = f2bf(val);
                csum[ni] += val;
            }
        }
    if (branch == 1){
        #pragma unroll
        for (int ni = 0; ni < 4; ni++){
            float v = csum[ni];
            v += __shfl_xor(v, 16);
            v += __shfl_xor(v, 32);
            if (g == 0) atomicAdd(&ksum[b*Cc + s0b + wn + ni*16 + l15], v);
        }
    }
}

// ---------------- T3t: transpose k,v to c-major ----------------
__global__ __launch_bounds__(256) void t3t_transpose(const short* __restrict__ qkT, const short* __restrict__ yvg,
                                                     short* __restrict__ kC, short* __restrict__ vC)
{
    int n0 = blockIdx.x * 64;
    int c0 = blockIdx.y * 64;
    int b  = blockIdx.z >> 1;
    int which = blockIdx.z & 1;
    const short* src; short* dst;
    if (which == 0){ src = qkT + (size_t)(b*NN + n0)*512 + 256 + c0; dst = kC + (size_t)(b*Cc + c0)*NN + n0; }
    else           { src = yvg + (size_t)(b*NN + n0)*512 +   0 + c0; dst = vC + (size_t)(b*Cc + c0)*NN + n0; }
    __shared__ __align__(16) short lds[64*72];
    int t = threadIdx.x;
    #pragma unroll
    for (int i = 0; i < 2; i++){
        int idx = i*256 + t;
        int n = idx >> 3, c8 = idx & 7;
        bf16x8 v = *(const bf16x8*)(src + (size_t)n*512 + c8*8);
        int key = (n ^ (n >> 3)) & 7;
        *(bf16x8*)(&lds[n*72 + (c8 ^ key)*8]) = v;
    }
    __syncthreads();
    #pragma unroll
    for (int i = 0; i < 2; i++){
        int idx = i*256 + t;
        int c = idx >> 3, n8 = idx & 7;
        bf16x8 pk;
        #pragma unroll
        for (int j = 0; j < 8; j++){
            int n = n8*8 + j;
            int key = (n ^ (n >> 3)) & 7;
            pk[j] = lds[n*72 + (((c >> 3) ^ key))*8 + (c & 7)];
        }
        *(bf16x8*)(dst + (size_t)c*NN + n8*8) = pk;
    }
}

// ---------------- T4: kv GEMM (atomic K-split) ----------------
__global__ __launch_bounds__(256) void t4_kv(const short* __restrict__ kC, const short* __restrict__ vC,
                                             float* __restrict__ kv)
{
    int m0 = blockIdx.x * 128;          // c
    int d0 = blockIdx.y * 128;          // d
    int b  = blockIdx.z >> 5;
    int nb = (blockIdx.z & 31) * 512;

    __shared__ __align__(16) short Al[128*32];
    __shared__ __align__(16) short Bl[128*32];
    int t = threadIdx.x, lane = t & 63, wid = t >> 6;
    int wm = (wid & 1) * 64, wn = (wid >> 1) * 64;
    int l15 = lane & 15, g = lane >> 4;
    int srow = wid*16 + (lane >> 2);
    int scol = (lane & 3) * 8;
    int sdst = wid*512 + lane*8;

    f32x4 acc[4][4];
    #pragma unroll
    for (int i=0;i<4;i++)
        #pragma unroll
        for (int j=0;j<4;j++){ acc[i][j][0]=0.f; acc[i][j][1]=0.f; acc[i][j][2]=0.f; acc[i][j][3]=0.f; }

    const short* ka = kC + (size_t)(b*Cc + m0)*NN + nb;
    const short* vb = vC + (size_t)(b*Cc + d0)*NN + nb;

    for (int k0 = 0; k0 < 512; k0 += 32){
        __syncthreads();
        #pragma unroll
        for (int i = 0; i < 2; i++){
            gload16(ka + (size_t)(i*64 + srow)*NN + k0 + scol, &Al[i*2048 + sdst]);
            gload16(vb + (size_t)(i*64 + srow)*NN + k0 + scol, &Bl[i*2048 + sdst]);
        }
        __syncthreads();
        bf16x8 bfr[4];
        #pragma unroll
        for (int ni = 0; ni < 4; ni++) bfr[ni] = *(const bf16x8*)(&Bl[(wn + ni*16 + l15)*32 + g*8]);
        #pragma unroll
        for (int mi = 0; mi < 4; mi++){
            bf16x8 a = *(const bf16x8*)(&Al[(wm + mi*16 + l15)*32 + g*8]);
            #pragma unroll
            for (int ni = 0; ni < 4; ni++)
                acc[mi][ni] = __builtin_amdgcn_mfma_f32_16x16x32_bf16(a, bfr[ni], acc[mi][ni], 0, 0, 0);
        }
    }
    #pragma unroll
    for (int mi = 0; mi < 4; mi++)
        #pragma unroll
        for (int ni = 0; ni < 4; ni++){
            int coll = wn + ni*16 + l15;
            #pragma unroll
            for (int r = 0; r < 4; r++){
                int row = wm + mi*16 + g*4 + r;
                atomicAdd(&kv[((size_t)b*Cc + m0 + row)*Cc + d0 + coll], acc[mi][ni][r]);
            }
        }
}

// ---------------- T4c: kvT16[d][c] = bf16(kv[c][d]/16) ----------------
__global__ __launch_bounds__(256) void t4c_kvT(const float* __restrict__ kv, short* __restrict__ kvT16)
{
    int d = blockIdx.x, b = blockIdx.y, c = threadIdx.x;
    float v = kv[((size_t)b*Cc + c)*Cc + d] * 0.0625f;
    kvT16[((size_t)b*Cc + d)*Cc + c] = f2bf(v);
}

// ---------------- T5: z = 1/(q.ksum/16 + N) ----------------
__global__ __launch_bounds__(256) void t5_z(const short* __restrict__ qkT, const float* __restrict__ ksum,
                                            float* __restrict__ z)
{
    int b = blockIdx.y;
    int n0 = blockIdx.x * 32;
    __shared__ float ks[256];
    int t = threadIdx.x;
    ks[t] = ksum[b*Cc + t];
    __syncthreads();
    int row = n0 + (t >> 3), l8 = t & 7;
    const short* q = qkT + (size_t)(b*NN + row)*512;
    float acc = 0.f;
    #pragma unroll
    for (int i = 0; i < 4; i++){
        int c8 = i*8 + l8;
        bf16x8 v = *(const bf16x8*)(q + c8*8);
        #pragma unroll
        for (int j = 0; j < 8; j++) acc += bf2f(v[j]) * ks[c8*8 + j];
    }
    acc += __shfl_down(acc, 4, 8);
    acc += __shfl_down(acc, 2, 8);
    acc += __shfl_down(acc, 1, 8);
    if (l8 == 0) z[b*NN + row] = 1.0f / (acc * 0.0625f + 16384.0f);
}

// ---------------- T6: final fused (q.kvT16, gate, Wo conv) ----------------
__global__ __launch_bounds__(256) void t6_final(const short* __restrict__ qkT, const short* __restrict__ kvT16,
    const short* __restrict__ yvg, const float* __restrict__ z,
    const short* __restrict__ wbf, const float* __restrict__ bo, float* __restrict__ out)
{
    int n0 = blockIdx.x * 64, b = blockIdx.y;
    __shared__ __align__(16) short Aq[64*32];
    __shared__ __align__(16) short Bw[256*32];
    __shared__ __align__(16) short S[64*264];
    int t = threadIdx.x, lane = t & 63, wid = t >> 6;
    int l15 = lane & 15, g = lane >> 4;
    const short* wo_bf = wbf + (size_t)6 * 65536;
    int srow = wid*16 + (lane >> 2);        // + i*64
    int scol = (lane & 3) * 8;
    int sdst = wid*512 + lane*8;            // + i*2048

    f32x4 acc[4][4];
    #pragma unroll
    for (int i=0;i<4;i++)
        #pragma unroll
        for (int j=0;j<4;j++){ acc[i][j][0]=0.f; acc[i][j][1]=0.f; acc[i][j][2]=0.f; acc[i][j][3]=0.f; }

    const short* qb = qkT + (size_t)(b*NN + n0)*512;
    const short* kvb = kvT16 + (size_t)b*Cc*Cc;

    // GEMM-a: t[n][d] = sum_c q[n][c] * kvT16[d][c]
    for (int k0 = 0; k0 < 256; k0 += 32){
        __syncthreads();
        gload16(qb + (size_t)srow*512 + k0 + scol, &Aq[sdst]);   // 64 rows, 1 issue
        #pragma unroll
        for (int i = 0; i < 4; i++)
            gload16(kvb + (size_t)(i*64 + srow)*Cc + k0 + scol, &Bw[i*2048 + sdst]);
        __syncthreads();
        bf16x8 bfr[4];
        #pragma unroll
        for (int ni = 0; ni < 4; ni++) bfr[ni] = *(const bf16x8*)(&Bw[(wid*64 + ni*16 + l15)*32 + g*8]);
        #pragma unroll
        for (int mi = 0; mi < 4; mi++){
            bf16x8 a = *(const bf16x8*)(&Aq[(mi*16 + l15)*32 + g*8]);
            #pragma unroll
            for (int ni = 0; ni < 4; ni++)
                acc[mi][ni] = __builtin_amdgcn_mfma_f32_16x16x32_bf16(a, bfr[ni], acc[mi][ni], 0, 0, 0);
        }
    }
    // epilogue-a: s = (t + v) * z * g  -> S[n][d]
    #pragma unroll
    for (int mi = 0; mi < 4; mi++)
        #pragma unroll
        for (int r = 0; r < 4; r++){
            int nl = mi*16 + g*4 + r;
            float zv = z[b*NN + n0 + nl];
            const short* vrow = yvg + (size_t)(b*NN + n0 + nl)*512;
            #pragma unroll
            for (int ni = 0; ni < 4; ni++){
                int d = wid*64 + ni*16 + l15;
                float vv = bf2f(vrow[d]);
                float gg = bf2f(vrow[256 + d]);
                S[nl*264 + d] = f2bf((acc[mi][ni][r] + vv) * zv * gg);
            }
        }
    __syncthreads();

    // GEMM-b: out[o][n] = sum_d Wo[o][d] * S[n][d] + bo
    f32x4 acc2[4][4];
    #pragma unroll
    for (int i=0;i<4;i++)
        #pragma unroll
        for (int j=0;j<4;j++){ acc2[i][j][0]=0.f; acc2[i][j][1]=0.f; acc2[i][j][2]=0.f; acc2[i][j][3]=0.f; }

    for (int k0 = 0; k0 < 256; k0 += 32){
        __syncthreads();
        #pragma unroll
        for (int i = 0; i < 4; i++)
            gload16(wo_bf + (size_t)(i*64 + srow)*Cc + k0 + scol, &Bw[i*2048 + sdst]);
        __syncthreads();
        bf16x8 sfr[4];
        #pragma unroll
        for (int ni = 0; ni < 4; ni++) sfr[ni] = *(const bf16x8*)(&S[(ni*16 + l15)*264 + k0 + g*8]);
        #pragma unroll
        for (int mi = 0; mi < 4; mi++){
            bf16x8 a = *(const bf16x8*)(&Bw[(wid*64 + mi*16 + l15)*32 + g*8]);
            #pragma unroll
            for (int ni = 0; ni < 4; ni++)
                acc2[mi][ni] = __builtin_amdgcn_mfma_f32_16x16x32_bf16(a, sfr[ni], acc2[mi][ni], 0, 0, 0);
        }
    }
    #pragma unroll
    for (int mi = 0; mi < 4; mi++)
        #pragma unroll
        for (int ni = 0; ni < 4; ni++){
            int n = n0 + ni*16 + l15;
            #pragma unroll
            for (int r = 0; r < 4; r++){
                int o = wid*64 + mi*16 + g*4 + r;
                out[((size_t)b*Cc + o)*NN + n] = acc2[mi][ni][r] + bo[o];
            }
        }
}

// ---------------- host ----------------
extern "C" void kernel_launch(void* const* d_in, const int* in_sizes, int n_in,
                              void* d_out, int out_size, void* d_ws, size_t ws_size,
                              hipStream_t stream)
{
    (void)in_sizes; (void)n_in; (void)out_size; (void)ws_size;
    const float* x   = (const float*)d_in[0];
    const float* Wq1 = (const float*)d_in[1];
    const float* bq1 = (const float*)d_in[2];
    const float* Wq2 = (const float*)d_in[3];
    const float* bq2 = (const float*)d_in[4];
    const float* Wk1 = (const float*)d_in[5];
    const float* bk1 = (const float*)d_in[6];
    const float* Wk2 = (const float*)d_in[7];
    const float* bk2 = (const float*)d_in[8];
    const float* Wv  = (const float*)d_in[9];
    const float* bv  = (const float*)d_in[10];
    const float* Wg  = (const float*)d_in[11];
    const float* bg  = (const float*)d_in[12];
    const float* Wo  = (const float*)d_in[13];
    const float* bo  = (const float*)d_in[14];
    float* out = (float*)d_out;

    char* ws = (char*)d_ws;
    float* mu    = (float*)(ws + 0);                //   4 KB
    float* rstd  = (float*)(ws + 4096);             //   4 KB
    float* z     = (float*)(ws + 8192);             // 256 KB  (ends 270336)
    short* kvT16 = (short*)(ws + 270336);           // 512 KB  (ends 794624)
    short* wbf   = (short*)(ws + 794624);           // 896 KB  bf16 weights (ends 1712128)
    float* ksum  = (float*)(ws + 1712128);          //   4 KB  (memset 0)
    float* kv    = (float*)(ws + 1716224);          //   1 MB  (memset 0, ends 2764800)
    short* xnT   = (short*)(ws + 3145728);          //  32 MB  (ends 36700160)
    short* y1qk  = (short*)(ws + 36700160);         //  64 MB  (ends 103809024)
    short* yvg   = (short*)(ws + 103809024);        //  64 MB  (ends 170917888)
    short* qkT   = (short*)(ws + 170917888);        //  64 MB  (ends 238026752)
    short* kC    = xnT;                             //  32 MB  (xnT dead after T2)
    short* vC    = y1qk;                            //  32 MB  (y1qk dead after T3)

    hipMemsetAsync(ws + 1712128, 0, 4096 + 1048576, stream);   // ksum + kv

    tw_conv      <<<dim3(64, 7),      256, 0, stream>>>(Wq1, Wk1, Wv, Wg, Wq2, Wk2, Wo, wbf);
    t0_stats     <<<dim3(1024),       256, 0, stream>>>(x, mu, rstd);
    t1_xnT       <<<dim3(256, 4, 4),  256, 0, stream>>>(x, mu, rstd, xnT);
    t2_conv1     <<<dim3(128, 8, 4),  256, 0, stream>>>(xnT, wbf, bq1, bk1, bv, bg, y1qk, yvg);
    t3_conv2     <<<dim3(128, 4, 4),  256, 0, stream>>>(y1qk, wbf, bq2, bk2, qkT, ksum);
    t3t_transpose<<<dim3(256, 4, 8),  256, 0, stream>>>(qkT, yvg, kC, vC);
    t4_kv        <<<dim3(2, 2, 128),  256, 0, stream>>>(kC, vC, kv);
    t4c_kvT      <<<dim3(256, 4),     256, 0, stream>>>(kv, kvT16);
    t5_z         <<<dim3(512, 4),     256, 0, stream>>>(qkT, ksum, z);
    t6_final     <<<dim3(256, 4),     256, 0, stream>>>(qkT, kvT16, yvg, z, wbf, bo, out);
}